// Round 10
// baseline (246.234 us; speedup 1.0000x reference)
//
#include <hip/hip_runtime.h>
#include <hip/hip_fp16.h>

using i32x4  = __attribute__((ext_vector_type(4)))  int;
using i32x16 = __attribute__((ext_vector_type(16))) int;

static constexpr int M  = 4 * 2048;   // 8192 rows (B*S)
static constexpr int N  = 4096;       // OUT_F
static constexpr int K  = 4096;       // IN_F
static constexpr int BM = 256, BN = 128, BK = 64;
static constexpr int NT = K / BK;         // 64 K-tiles
static constexpr int ATILE = BM * BK;     // 16384 B packed A tile
static constexpr int BTILE = BN * BK;     //  8192 B packed B tile

// ---------------- fused pack kernel: int32 -> blocked int8 tiles -------------
// A tile (16 KB): [kg(4)][row(256)][16B]   wa: [M/256][NT][ATILE]
// B tile ( 8 KB): [kg(4)][col(128)][16B]   wb: [N/128][NT][BTILE] (transposed)
static constexpr int PX_BLOCKS = (int)((size_t)M * K / 16 / 256);  // 8192
static constexpr int PW_BLOCKS = (int)((size_t)N * K / 16 / 256);  // 4096

__device__ __forceinline__ unsigned pack4(i32x4 v) {
  return (unsigned)((v.x & 255) | ((v.y & 255) << 8) | ((v.z & 255) << 16) | (v.w << 24));
}

__global__ __launch_bounds__(256) void pack_kernel(const int* __restrict__ x,
                                                   const int* __restrict__ w,
                                                   unsigned char* __restrict__ wa,
                                                   unsigned char* __restrict__ wb) {
  if (blockIdx.x < PX_BLOCKS) {
    unsigned g = blockIdx.x * 256 + threadIdx.x;   // dest 16B granule, < M*K/16
    unsigned row = g & 255;
    unsigned kg  = (g >> 8) & 3;
    unsigned kt  = (g >> 10) & 63;
    unsigned br  = g >> 16;
    const int* src = x + ((size_t)(br * 256 + row) * K + kt * 64 + kg * 16);
    i32x4 v0 = *(const i32x4*)(src + 0);
    i32x4 v1 = *(const i32x4*)(src + 4);
    i32x4 v2 = *(const i32x4*)(src + 8);
    i32x4 v3 = *(const i32x4*)(src + 12);
    i32x4 d;
    d.x = (int)pack4(v0); d.y = (int)pack4(v1); d.z = (int)pack4(v2); d.w = (int)pack4(v3);
    *(i32x4*)(wa + (size_t)g * 16) = d;
  } else {
    unsigned g = (blockIdx.x - PX_BLOCKS) * 256 + threadIdx.x;  // < N*K/16
    unsigned col = g & 127;
    unsigned kg  = (g >> 7) & 3;
    unsigned kt  = (g >> 9) & 63;
    unsigned bn  = g >> 15;
    unsigned n   = bn * 128 + col;
    unsigned k0  = kt * 64 + kg * 16;
    const int* src = w + (size_t)k0 * N + n;
    i32x4 d;
#pragma unroll
    for (int j = 0; j < 4; ++j) {
      int b0 = src[(size_t)(j * 4 + 0) * N];
      int b1 = src[(size_t)(j * 4 + 1) * N];
      int b2 = src[(size_t)(j * 4 + 2) * N];
      int b3 = src[(size_t)(j * 4 + 3) * N];
      d[j] = (b0 & 255) | ((b1 & 255) << 8) | ((b2 & 255) << 16) | (b3 << 24);
    }
    *(i32x4*)(wb + (size_t)g * 16) = d;
  }
}

// -- GEMM: 256x128 block, 4 waves (2x2, wave 128x64, acc[4][2]), reg-staged ---
// dbuf LDS 48 KB; __launch_bounds__(256,3) -> 3 blocks/CU (144 KB LDS, 12 waves)

__global__ __launch_bounds__(256, 3) void gemm_i8(const unsigned char* __restrict__ wa,
                                                  const unsigned char* __restrict__ wb,
                                                  const __half* __restrict__ bias,
                                                  const float* __restrict__ alphaP,
                                                  float* __restrict__ out) {
  __shared__ __align__(16) unsigned char As[2][ATILE];   // 32 KB
  __shared__ __align__(16) unsigned char Bs[2][BTILE];   // 16 KB -> 48 KB total

  const int tid  = threadIdx.x;
  const int lane = tid & 63;
  const int w    = tid >> 6;            // wave 0..3
  const int wr   = w >> 1, wc = w & 1;  // 2 x 2 grid; wave tile 128 x 64
  const int l31  = lane & 31;
  const int kgl  = lane >> 5;

  const int bc = blockIdx.x;            // 0..31 (fast: neighbors share A panel)
  const int br = blockIdx.y;            // 0..31

  const unsigned char* ga = wa + (size_t)br * NT * ATILE;
  const unsigned char* gb = wb + (size_t)bc * NT * BTILE;

  // reg staging: A 1024 granules -> 4/thread; B 512 granules -> 2/thread
  i32x4 s0, s1, s2, s3, s4, s5;

#define GLOAD(T) do {                                                \
    const i32x4* ap = (const i32x4*)(ga + (size_t)(T) * ATILE);      \
    const i32x4* bp = (const i32x4*)(gb + (size_t)(T) * BTILE);      \
    s0 = ap[tid]; s1 = ap[tid + 256];                                \
    s2 = ap[tid + 512]; s3 = ap[tid + 768];                          \
    s4 = bp[tid]; s5 = bp[tid + 256];                                \
  } while (0)

#define SWRITE(BUF) do {                                             \
    i32x4* aw = (i32x4*)&As[BUF][0];                                 \
    i32x4* bw = (i32x4*)&Bs[BUF][0];                                 \
    aw[tid] = s0; aw[tid + 256] = s1;                                \
    aw[tid + 512] = s2; aw[tid + 768] = s3;                          \
    bw[tid] = s4; bw[tid + 256] = s5;                                \
  } while (0)

  GLOAD(0);
  SWRITE(0);
  __syncthreads();

  i32x16 acc[4][2] = {};

  const int arow = wr * 128 + l31;      // A frag row base (per lane)
  const int bcol = wc * 64 + l31;       // B frag col base (per lane)

  for (int t = 0; t < NT; ++t) {
    const int cur = t & 1;
    if (t + 1 < NT) GLOAD(t + 1);       // issue early: latency hides under MFMA

    const unsigned char* Ab = &As[cur][0] + kgl * 4096;   // [kg][row(256)][16]
    const unsigned char* Bb = &Bs[cur][0] + kgl * 2048;   // [kg][col(128)][16]
#pragma unroll
    for (int kc = 0; kc < 2; ++kc) {    // kg = kc*2 + kgl
      const unsigned char* Ap = Ab + kc * 8192;
      const unsigned char* Bp = Bb + kc * 4096;
      i32x4 a0 = *(const i32x4*)(Ap + (arow +  0) * 16);
      i32x4 a1 = *(const i32x4*)(Ap + (arow + 32) * 16);
      i32x4 a2 = *(const i32x4*)(Ap + (arow + 64) * 16);
      i32x4 a3 = *(const i32x4*)(Ap + (arow + 96) * 16);
      i32x4 b0 = *(const i32x4*)(Bp + (bcol +  0) * 16);
      i32x4 b1 = *(const i32x4*)(Bp + (bcol + 32) * 16);
      acc[0][0] = __builtin_amdgcn_mfma_i32_32x32x32_i8(a0, b0, acc[0][0], 0, 0, 0);
      acc[0][1] = __builtin_amdgcn_mfma_i32_32x32x32_i8(a0, b1, acc[0][1], 0, 0, 0);
      acc[1][0] = __builtin_amdgcn_mfma_i32_32x32x32_i8(a1, b0, acc[1][0], 0, 0, 0);
      acc[1][1] = __builtin_amdgcn_mfma_i32_32x32x32_i8(a1, b1, acc[1][1], 0, 0, 0);
      acc[2][0] = __builtin_amdgcn_mfma_i32_32x32x32_i8(a2, b0, acc[2][0], 0, 0, 0);
      acc[2][1] = __builtin_amdgcn_mfma_i32_32x32x32_i8(a2, b1, acc[2][1], 0, 0, 0);
      acc[3][0] = __builtin_amdgcn_mfma_i32_32x32x32_i8(a3, b0, acc[3][0], 0, 0, 0);
      acc[3][1] = __builtin_amdgcn_mfma_i32_32x32x32_i8(a3, b1, acc[3][1], 0, 0, 0);
    }

    // no sched_barrier: let the compiler sink ds_writes into the MFMA tail
    // (vmcnt dependency on s0..s5 already orders them after GLOAD returns)
    if (t + 1 < NT) SWRITE(cur ^ 1);
    __syncthreads();
  }

  // epilogue: C/D layout col=lane&31, row=(r&3)+8*(r>>2)+4*(lane>>5)
  const float alpha = *alphaP;
  const int row0 = br * 256 + wr * 128 + 4 * kgl;
  const int col0 = bc * 128 + wc * 64 + l31;
#pragma unroll
  for (int ni = 0; ni < 2; ++ni) {
    const int col = col0 + ni * 32;
    const float bf = __half2float(bias[col]);
#pragma unroll
    for (int mi = 0; mi < 4; ++mi) {
#pragma unroll
      for (int r = 0; r < 16; ++r) {
        const int row = row0 + mi * 32 + (r & 3) + 8 * (r >> 2);
        out[(size_t)row * N + col] = ((float)acc[mi][ni][r] + bf) * alpha;
      }
    }
  }
#undef GLOAD
#undef SWRITE
}

extern "C" void kernel_launch(void* const* d_in, const int* in_sizes, int n_in,
                              void* d_out, int out_size, void* d_ws, size_t ws_size,
                              hipStream_t stream) {
  const int*    x     = (const int*)d_in[0];
  const int*    wgt   = (const int*)d_in[1];
  const __half* bias  = (const __half*)d_in[2];
  const float*  alpha = (const float*)d_in[3];
  float*        out   = (float*)d_out;

  // workspace: packed A (32 MB) + packed B (16 MB) = 48 MB
  unsigned char* wa = (unsigned char*)d_ws;
  unsigned char* wb = wa + (size_t)M * K;

  pack_kernel<<<PX_BLOCKS + PW_BLOCKS, 256, 0, stream>>>(x, wgt, wa, wb);

  dim3 grid(N / BN, M / BM);   // 32 x 32 = 1024 blocks, 3 resident/CU
  gemm_i8<<<grid, 256, 0, stream>>>(wa, wb, bias, alpha, out);
}

// Round 11
// 221.698 us; speedup vs baseline: 1.1107x; 1.1107x over previous
//
#include <hip/hip_runtime.h>
#include <hip/hip_fp16.h>

using i32x4  = __attribute__((ext_vector_type(4)))  int;
using i32x16 = __attribute__((ext_vector_type(16))) int;

static constexpr int M  = 4 * 2048;   // 8192 rows (B*S)
static constexpr int N  = 4096;       // OUT_F
static constexpr int K  = 4096;       // IN_F
static constexpr int BM = 128, BN = 128, BK = 64;
static constexpr int NT = K / BK;     // 64 K-tiles
static constexpr int TILE = BM * BK;  // 8192 bytes per packed int8 tile

// ---------------- fused pack kernel: int32 -> blocked int8 tiles -------------
// tile (8 KB): [kg(4)][row(128)][16B]  wa: [M/128][NT][tile], wb: [N/128][NT][tile]
static constexpr int PX_BLOCKS = (int)((size_t)M * K / 16 / 256);  // 8192
static constexpr int PW_BLOCKS = (int)((size_t)N * K / 16 / 256);  // 4096

__device__ __forceinline__ unsigned pack4(i32x4 v) {
  return (unsigned)((v.x & 255) | ((v.y & 255) << 8) | ((v.z & 255) << 16) | (v.w << 24));
}

__global__ __launch_bounds__(256) void pack_kernel(const int* __restrict__ x,
                                                   const int* __restrict__ w,
                                                   unsigned char* __restrict__ wa,
                                                   unsigned char* __restrict__ wb) {
  if (blockIdx.x < PX_BLOCKS) {
    unsigned g = blockIdx.x * 256 + threadIdx.x;     // dest 16B granule, < M*K/16
    unsigned tile = g >> 9, gt = g & 511;
    unsigned kg = gt >> 7, row = gt & 127;
    unsigned br = tile >> 6, kt = tile & 63;
    const int* src = x + ((size_t)(br * 128 + row) * K + kt * 64 + kg * 16);
    i32x4 v0 = *(const i32x4*)(src + 0);
    i32x4 v1 = *(const i32x4*)(src + 4);
    i32x4 v2 = *(const i32x4*)(src + 8);
    i32x4 v3 = *(const i32x4*)(src + 12);
    i32x4 d;
    d.x = (int)pack4(v0); d.y = (int)pack4(v1); d.z = (int)pack4(v2); d.w = (int)pack4(v3);
    *(i32x4*)(wa + (size_t)g * 16) = d;
  } else {
    unsigned g = (blockIdx.x - PX_BLOCKS) * 256 + threadIdx.x;  // < N*K/16
    unsigned tile = g >> 9, gt = g & 511;
    unsigned kg = gt >> 7, col = gt & 127;
    unsigned bn = tile >> 6, kt = tile & 63;
    unsigned n  = bn * 128 + col;
    unsigned k0 = kt * 64 + kg * 16;
    const int* src = w + (size_t)k0 * N + n;
    i32x4 d;
#pragma unroll
    for (int j = 0; j < 4; ++j) {
      int b0 = src[(size_t)(j * 4 + 0) * N];
      int b1 = src[(size_t)(j * 4 + 1) * N];
      int b2 = src[(size_t)(j * 4 + 2) * N];
      int b3 = src[(size_t)(j * 4 + 3) * N];
      d[j] = (b0 & 255) | ((b1 & 255) << 8) | ((b2 & 255) << 16) | (b3 << 24);
    }
    *(i32x4*)(wb + (size_t)g * 16) = d;
  }
}

// -- GEMM: 128x128, 4 waves (2x2), A reg-staged via LDS, B DIRECT global->VGPR

__global__ __launch_bounds__(256) void gemm_i8(const unsigned char* __restrict__ wa,
                                               const unsigned char* __restrict__ wb,
                                               const __half* __restrict__ bias,
                                               const float* __restrict__ alphaP,
                                               float* __restrict__ out) {
  __shared__ __align__(16) unsigned char As[2][TILE];   // 16 KB total (A only)

  const int tid  = threadIdx.x;
  const int lane = tid & 63;
  const int w    = tid >> 6;            // wave 0..3
  const int wr   = w >> 1, wc = w & 1;  // 2 x 2 grid; wave tile 64 x 64
  const int l31  = lane & 31;
  const int kgl  = lane >> 5;

  const int bc = blockIdx.x;            // 0..31 (fast: neighbors share A panel)
  const int br = blockIdx.y;            // 0..63

  const unsigned char* ga = wa + (size_t)br * NT * TILE;
  const unsigned char* gb = wb + (size_t)bc * NT * TILE;

  const int arow = wr * 64 + l31;       // A frag row base (per lane)
  const int bcol = wc * 64 + l31;       // B frag col base (per lane)

  // A reg staging: 8KB tile / 256 threads = 2 x 16B per thread
  i32x4 s0, s1;
  // B direct: [parity][kc][ni], all indices compile-time constant
  i32x4 b[2][2][2];

#define GLOADA(T) do {                                               \
    const i32x4* ap = (const i32x4*)(ga + (size_t)(T) * TILE);       \
    s0 = ap[tid]; s1 = ap[tid + 256];                                \
  } while (0)

#define BLOAD(PAR, T) do {                                           \
    const unsigned char* bt = gb + (size_t)(T) * TILE;               \
    b[PAR][0][0] = *(const i32x4*)(bt + (kgl    ) * 2048 + (bcol +  0) * 16); \
    b[PAR][0][1] = *(const i32x4*)(bt + (kgl    ) * 2048 + (bcol + 32) * 16); \
    b[PAR][1][0] = *(const i32x4*)(bt + (kgl + 2) * 2048 + (bcol +  0) * 16); \
    b[PAR][1][1] = *(const i32x4*)(bt + (kgl + 2) * 2048 + (bcol + 32) * 16); \
  } while (0)

#define SWRITE(BUF) do {                                             \
    i32x4* aw = (i32x4*)&As[BUF][0];                                 \
    aw[tid] = s0; aw[tid + 256] = s1;                                \
  } while (0)

  GLOADA(0);
  BLOAD(0, 0);
  SWRITE(0);          // compiler inserts vmcnt before the ds_writes
  __syncthreads();

  i32x16 acc[2][2] = {};

#define STEP(T, PAR) do {                                                      \
    if ((T) + 1 < NT) { GLOADA((T) + 1); BLOAD(PAR ^ 1, (T) + 1); }            \
    const unsigned char* Ab = &As[(T) & 1][0] + kgl * 2048;                    \
    {                                                                          \
      const unsigned char* Ap = Ab;               /* kc0 */                    \
      i32x4 a0 = *(const i32x4*)(Ap + (arow +  0) * 16);                       \
      i32x4 a1 = *(const i32x4*)(Ap + (arow + 32) * 16);                       \
      acc[0][0] = __builtin_amdgcn_mfma_i32_32x32x32_i8(a0, b[PAR][0][0], acc[0][0], 0, 0, 0); \
      acc[0][1] = __builtin_amdgcn_mfma_i32_32x32x32_i8(a0, b[PAR][0][1], acc[0][1], 0, 0, 0); \
      acc[1][0] = __builtin_amdgcn_mfma_i32_32x32x32_i8(a1, b[PAR][0][0], acc[1][0], 0, 0, 0); \
      acc[1][1] = __builtin_amdgcn_mfma_i32_32x32x32_i8(a1, b[PAR][0][1], acc[1][1], 0, 0, 0); \
    }                                                                          \
    {                                                                          \
      const unsigned char* Ap = Ab + 4096;        /* kc1 */                    \
      i32x4 a0 = *(const i32x4*)(Ap + (arow +  0) * 16);                       \
      i32x4 a1 = *(const i32x4*)(Ap + (arow + 32) * 16);                       \
      acc[0][0] = __builtin_amdgcn_mfma_i32_32x32x32_i8(a0, b[PAR][1][0], acc[0][0], 0, 0, 0); \
      acc[0][1] = __builtin_amdgcn_mfma_i32_32x32x32_i8(a0, b[PAR][1][1], acc[0][1], 0, 0, 0); \
      acc[1][0] = __builtin_amdgcn_mfma_i32_32x32x32_i8(a1, b[PAR][1][0], acc[1][0], 0, 0, 0); \
      acc[1][1] = __builtin_amdgcn_mfma_i32_32x32x32_i8(a1, b[PAR][1][1], acc[1][1], 0, 0, 0); \
    }                                                                          \
    /* keep gload issue + frag reads + MFMAs above; vmcnt-wait + ds_write below */ \
    __builtin_amdgcn_sched_barrier(0);                                         \
    if ((T) + 1 < NT) SWRITE(((T) & 1) ^ 1);                                   \
    __syncthreads();                                                           \
  } while (0)

  for (int t = 0; t < NT; t += 2) {   // NT even; parity keeps b[] indices constant
    STEP(t, 0);
    STEP(t + 1, 1);
  }

  // epilogue: C/D layout col=lane&31, row=(r&3)+8*(r>>2)+4*(lane>>5)
  const float alpha = *alphaP;
  const int row0 = br * 128 + wr * 64 + 4 * kgl;
  const int col0 = bc * 128 + wc * 64 + l31;
#pragma unroll
  for (int ni = 0; ni < 2; ++ni) {
    const int col = col0 + ni * 32;
    const float bf = __half2float(bias[col]);
#pragma unroll
    for (int mi = 0; mi < 2; ++mi) {
#pragma unroll
      for (int r = 0; r < 16; ++r) {
        const int row = row0 + mi * 32 + (r & 3) + 8 * (r >> 2);
        out[(size_t)row * N + col] = ((float)acc[mi][ni][r] + bf) * alpha;
      }
    }
  }
#undef STEP
#undef GLOADA
#undef BLOAD
#undef SWRITE
}

extern "C" void kernel_launch(void* const* d_in, const int* in_sizes, int n_in,
                              void* d_out, int out_size, void* d_ws, size_t ws_size,
                              hipStream_t stream) {
  const int*    x     = (const int*)d_in[0];
  const int*    wgt   = (const int*)d_in[1];
  const __half* bias  = (const __half*)d_in[2];
  const float*  alpha = (const float*)d_in[3];
  float*        out   = (float*)d_out;

  // workspace: packed A (32 MB) + packed B (16 MB) = 48 MB
  unsigned char* wa = (unsigned char*)d_ws;
  unsigned char* wb = wa + (size_t)M * K;

  pack_kernel<<<PX_BLOCKS + PW_BLOCKS, 256, 0, stream>>>(x, wgt, wa, wb);

  dim3 grid(N / BN, M / BM);   // 32 x 64 = 2048 blocks
  gemm_i8<<<grid, 256, 0, stream>>>(wa, wb, bias, alpha, out);
}